// Round 16
// baseline (121.915 us; speedup 1.0000x reference)
//
#include <hip/hip_runtime.h>
#include <hip/hip_bf16.h>
#include <hip/hip_fp8.h>
#include <math.h>

#define BROWS 4096
#define DIM   512
#define YEMB_B 2097152   // 4096*512 bytes, offset of emb rows in Yq (fp8)
#define TSTRIDE 191      // tile stride (tiles are 192 wide, overlap by 1)
#define NT 22            // tiles per dim; triangle blocks = 22*23/2 = 253

typedef float f32x4 __attribute__((ext_vector_type(4)));

// ---------------------------------------------------------------------------
// prep4: wave-per-row, no barriers. 8192 rows (low then emb), 4 rows/block.
// L2-normalize -> fp8 e4m3 row in Yq; s=sum(y^2), r=sum(y) from f32 y.
// (verified R12-R27: absmax 0.0)
// ---------------------------------------------------------------------------
__global__ __launch_bounds__(256) void prep4_kernel(
    const float* __restrict__ low, const float* __restrict__ emb,
    unsigned char* __restrict__ Yq,
    float* __restrict__ s_l, float* __restrict__ r_l,
    float* __restrict__ s_e, float* __restrict__ r_e,
    float* __restrict__ out) {
  const int tid = threadIdx.x;
  const int lane = tid & 63, wid = tid >> 6;
  const int rid = blockIdx.x * 4 + wid;          // 0..8191
  if (blockIdx.x == 0 && tid == 0) out[0] = 0.f;

  const bool is_low = (rid < BROWS);
  const int row = is_low ? rid : rid - BROWS;
  const float* x = (is_low ? low : emb) + (size_t)row * DIM;

  const float4 v0 = ((const float4*)x)[lane * 2];
  const float4 v1 = ((const float4*)x)[lane * 2 + 1];

  float ss = v0.x * v0.x + v0.y * v0.y + v0.z * v0.z + v0.w * v0.w +
             v1.x * v1.x + v1.y * v1.y + v1.z * v1.z + v1.w * v1.w;
#pragma unroll
  for (int o = 1; o < 64; o <<= 1) ss += __shfl_xor(ss, o, 64);
  const float inv = 1.0f / fmaxf(sqrtf(ss), 1e-12f);

  float y[8] = {v0.x * inv, v0.y * inv, v0.z * inv, v0.w * inv,
                v1.x * inv, v1.y * inv, v1.z * inv, v1.w * inv};

  union { unsigned char b[8]; unsigned long long u; } pk;
  float sv = 0.f, rv = 0.f;
#pragma unroll
  for (int i = 0; i < 8; ++i) {
    pk.b[i] = __hip_fp8_e4m3(y[i]).__x;   // OCP e4m3fn, HW RNE
    sv += y[i] * y[i];
    rv += y[i];
  }
  ((unsigned long long*)(Yq + (size_t)rid * 512))[lane] = pk.u;

#pragma unroll
  for (int o = 1; o < 64; o <<= 1) {
    sv += __shfl_xor(sv, o, 64);
    rv += __shfl_xor(rv, o, 64);
  }
  if (lane == 0) {
    (is_low ? s_l : s_e)[row] = sv;
    (is_low ? r_l : r_e)[row] = rv;
  }
}

// ---------------------------------------------------------------------------
// R31 = resubmit of R28 (rounds 13-15 benches never acquired a GPU).
// R18 base (twice-verified 108.46/108.88 us, fused 44.84/45.2, absmax 0.0)
// + ONE structural change: A-panel DIRECT-TO-REGISTER.
// Rationale: R27 showed FETCH_SIZE -27% with zero time delta (HBM/L3 path
// not the bound); time tracks the serialized per-round phase chain. Each
// wave consumes only its own 48 A-rows -> LDS round-trip for A is pure
// overhead. A frags now load global->VGPR (double-buffered 1 round ahead):
//   global byte = row*512 + 64t + 32kk + (quad>>1)*16 + (quad&1)*8,
//   row = min(r0+48wr+16u+cpos, 4095)   [decode verified vs R18 LDS map]
// Effects: staging 6->3 global_load_lds/thread/round; LDS 96->48 KB dbuf;
// ds_read per kk 18->12; diag special-case gone (uniform vmcnt(15): 3 B-
// stage + 12 A-loads in flight for t+1); A has no lgkmcnt gate before MFMA.
// Static reg double-buffer via unroll-by-2 (no runtime-indexed arrays).
// Everything else (B staging/swizzle, epilogue, hands, reduce) R18-identical.
// Reg budget ~172 VGPR + 144 unified-acc < cap (512,2). LDS ~57 KB.
// Falsifier: WRITE_SIZE must stay ~8 KB (spill signature = R22's 75 MB).
// ---------------------------------------------------------------------------
__global__ __launch_bounds__(512, 2) void fused_sym_kernel(
    const unsigned char* __restrict__ Yq,
    const float* __restrict__ s_l, const float* __restrict__ r_l,
    const float* __restrict__ s_e, const float* __restrict__ r_e,
    float* __restrict__ out) {
  __shared__ __align__(16) unsigned char lds8[49152];  // 2 x 24 KB B buffers
  __shared__ float hand_d[4][48][2];    // dl/de at tile col 96, per wr
  __shared__ float hand_t[4][192][2];   // dl/de at tile row 48*wr ([wr-1])
  __shared__ float sred[8];

  // decode upper-triangle block id
  int rem = blockIdx.x, br = 0;
  while (rem >= NT - br) { rem -= NT - br; ++br; }
  const int bc = br + rem;
  const bool diag = (br == bc);

  const int tid = threadIdx.x;
  const int lane = tid & 63;
  const int wid = tid >> 6;          // 0..7
  const int wr = wid >> 1;           // 0..3: rows 48*wr..48*wr+47
  const int wc = wid & 1;            // 0..1: cols 96*wc..96*wc+95
  const int quad = lane >> 4, cpos = lane & 15;
  const int r0 = br * TSTRIDE, c0 = bc * TSTRIDE;

  // ---- B staging: 1536 slots of 16B per round (2 segs x 96 rp x 8 chunks);
  // thread owns slot c = tid + 512*s, s=0..2. ----
  int goff[3];   // BYTE offsets into Yq (add k0 = t*64 per round)
#pragma unroll
  for (int s = 0; s < 3; ++s) {
    const int c = tid + 512 * s;          // 0..1535
    const int seg = c / 768;              // 0 = B_low, 1 = B_emb
    const int within = c - seg * 768;
    const int rp = within >> 3;           // 0..95
    const int cc = within & 7;
    const int rloc = 2 * rp + (cc >> 2);
    const int gch = (cc & 3) ^ (rp & 3);  // swizzle
    const int base = (seg ? YEMB_B : 0) + min(c0 + rloc, BROWS - 1) * 512;
    goff[s] = base + (gch << 4);
  }

  auto STAGE = [&](int t, int b) {
    const int k0 = t * 64;
#pragma unroll
    for (int s = 0; s < 3; ++s)
      __builtin_amdgcn_global_load_lds(
          (const __attribute__((address_space(1))) void*)(Yq + goff[s] + k0),
          (__attribute__((address_space(3))) void*)(lds8 + b * 24576 +
                                                    (tid + 512 * s) * 16),
          16, 0, 0);
  };

  // ---- A direct-to-register: per-(u) global byte offsets into Yq ----
  int aoffg[3];
#pragma unroll
  for (int u = 0; u < 3; ++u)
    aoffg[u] = min(r0 + 48 * wr + 16 * u + cpos, BROWS - 1) * 512 +
               (quad >> 1) * 16 + (quad & 1) * 8;

  auto ALOAD = [&](int t, long (&aL)[6], long (&aE)[6]) {
#pragma unroll
    for (int u = 0; u < 3; ++u)
#pragma unroll
      for (int kk = 0; kk < 2; ++kk) {
        const int o = aoffg[u] + t * 64 + kk * 32;
        aL[u * 2 + kk] = *(const long*)(Yq + o);
        aE[u * 2 + kk] = *(const long*)(Yq + YEMB_B + o);
      }
  };

  // ---- B frag addressing (per 24 KB buffer): B_low 0, B_emb 12288;
  // row-pair stride 128 B; v stride 16 rows = 8 rp = 1024 B. ----
  const int RbH = (96 * wc + cpos) >> 1;
  const int s3b = RbH & 3;
  const int boff = RbH * 128 + (cpos & 1) * 64 + (quad & 1) * 8;

  f32x4 accl[3][6], acce[3][6];
#pragma unroll
  for (int u = 0; u < 3; ++u)
#pragma unroll
    for (int v = 0; v < 6; ++v) {
      accl[u][v] = (f32x4)(0.f);
      acce[u][v] = (f32x4)(0.f);
    }

  long aL0[6], aE0[6], aL1[6], aE1[6];
  STAGE(0, 0);          // prologue: B(0) -> buf0 (3 ops)
  ALOAD(0, aL0, aE0);   //           A(0) -> regs  (12 ops)

  auto ROUND = [&](int t, long (&aLc)[6], long (&aEc)[6],
                   long (&aLn)[6], long (&aEn)[6]) {
    if (t < 7) {
      STAGE(t + 1, (t + 1) & 1);   // 3 ops
      ALOAD(t + 1, aLn, aEn);      // 12 ops
    }
    // counted wait: keep t+1's 15 ops in flight; round-t's are drained.
    if (t == 7) asm volatile("s_waitcnt vmcnt(0)" ::: "memory");
    else        asm volatile("s_waitcnt vmcnt(15)" ::: "memory");
    __builtin_amdgcn_s_barrier();
    __builtin_amdgcn_sched_barrier(0);

    const unsigned char* Lb = lds8 + (t & 1) * 24576;
#pragma unroll
    for (int kk = 0; kk < 2; ++kk) {
      const int q = 2 * kk + (quad >> 1);          // 16B chunk 0..3
      const int chb = boff + ((q ^ s3b) << 4);
      {  // low matrix
        long b[6];
#pragma unroll
        for (int v = 0; v < 6; ++v) b[v] = *(const long*)(Lb + chb + v * 1024);
        __builtin_amdgcn_s_setprio(1);
#pragma unroll
        for (int u = 0; u < 3; ++u)
#pragma unroll
          for (int v = 0; v < 6; ++v)
            accl[u][v] = __builtin_amdgcn_mfma_f32_16x16x32_fp8_fp8(
                aLc[u * 2 + kk], b[v], accl[u][v], 0, 0, 0);
        __builtin_amdgcn_s_setprio(0);
      }
      {  // emb matrix
        long b[6];
#pragma unroll
        for (int v = 0; v < 6; ++v)
          b[v] = *(const long*)(Lb + 12288 + chb + v * 1024);
        __builtin_amdgcn_s_setprio(1);
#pragma unroll
        for (int u = 0; u < 3; ++u)
#pragma unroll
          for (int v = 0; v < 6; ++v)
            acce[u][v] = __builtin_amdgcn_mfma_f32_16x16x32_fp8_fp8(
                aEc[u * 2 + kk], b[v], acce[u][v], 0, 0, 0);
        __builtin_amdgcn_s_setprio(0);
      }
    }
    __builtin_amdgcn_sched_barrier(0);
    __builtin_amdgcn_s_barrier();
    __builtin_amdgcn_sched_barrier(0);
  };

#pragma unroll
  for (int tt = 0; tt < 4; ++tt) {   // static reg double-buffer (rule #20)
    ROUND(2 * tt,     aL0, aE0, aL1, aE1);
    ROUND(2 * tt + 1, aL1, aE1, aL0, aE0);
  }

  // ---- transform both accs -> distances in place ----
  const float epst = (float)DIM * 1e-6f * 1e-6f;
#pragma unroll
  for (int v = 0; v < 6; ++v) {
    const int j = min(c0 + 96 * wc + 16 * v + cpos, BROWS - 1);
    const float sjl = s_l[j], rjl = r_l[j];
    const float sje = s_e[j], rje = r_e[j];
#pragma unroll
    for (int u = 0; u < 3; ++u)
#pragma unroll
      for (int r = 0; r < 4; ++r) {
        const int i = min(r0 + 48 * wr + 16 * u + 4 * quad + r, BROWS - 1);
        const float sql = s_l[i] + sjl - 2.f * accl[u][v][r] +
                          2e-6f * (r_l[i] - rjl) + epst;
        accl[u][v][r] = sqrtf(fmaxf(sql, 0.f));
        const float sqe = s_e[i] + sje - 2.f * acce[u][v][r] +
                          2e-6f * (r_e[i] - rje) + epst;
        acce[u][v][r] = sqrtf(fmaxf(sqe, 0.f));
      }
  }
  // now: dl in accl, de in acce

  // ---- publish cross-wave boundary values (dl and de) ----
  if (wc == 1 && cpos == 0) {   // tile col 96 for this wr's 48 rows
#pragma unroll
    for (int u = 0; u < 3; ++u)
#pragma unroll
      for (int r = 0; r < 4; ++r) {
        hand_d[wr][16 * u + 4 * quad + r][0] = accl[u][0][r];
        hand_d[wr][16 * u + 4 * quad + r][1] = acce[u][0][r];
      }
  }
  if (quad == 0 && wr >= 1) {   // tile row 48*wr (u=0,r=0) for 96 cols
#pragma unroll
    for (int v = 0; v < 6; ++v) {
      hand_t[wr - 1][96 * wc + 16 * v + cpos][0] = accl[0][v][0];
      hand_t[wr - 1][96 * wc + 16 * v + cpos][1] = acce[0][v][0];
    }
  }
  __syncthreads();

  float sum = 0.f;

  // ---- pass 1: direct terms (i in rows, pair cols j,j+1) ----
  const int srcin = (lane & 48) | ((cpos + 1) & 15);
#pragma unroll
  for (int u = 0; u < 3; ++u)
#pragma unroll
    for (int r = 0; r < 4; ++r) {
      const int trow = 48 * wr + 16 * u + 4 * quad + r;
      const int i = r0 + trow;
      const bool rowok = (trow <= TSTRIDE - 1) && (i <= BROWS - 2);
#pragma unroll
      for (int v = 0; v < 6; ++v) {
        const float dl1 = accl[u][v][r], de1 = acce[u][v][r];
        float dl2 = __shfl(dl1, srcin, 64);
        float de2 = __shfl(de1, srcin, 64);
        if (v < 5) {
          const float dlb = __shfl(accl[u][v + 1][r], lane & 48, 64);
          const float deb = __shfl(acce[u][v + 1][r], lane & 48, 64);
          if (cpos == 15) { dl2 = dlb; de2 = deb; }
        } else if (cpos == 15 && wc == 0) {
          dl2 = hand_d[wr][16 * u + 4 * quad + r][0];
          de2 = hand_d[wr][16 * u + 4 * quad + r][1];
        }
        const int tcol = 96 * wc + 16 * v + cpos;
        const int j = c0 + tcol;
        if (rowok && tcol <= TSTRIDE - 1 && j <= BROWS - 3) {
          const float aa = dl1 - dl2, bb = de1 - de2;
          const float coeff = (float)((aa > 0.f) - (aa < 0.f)) -
                              (float)((bb > 0.f) - (bb < 0.f));
          sum += coeff * (de2 - de1);
        }
      }
    }

  // ---- pass 2: transposed terms (i in cols, pair rows j,j+1), off-diag only ----
  if (!diag) {
#pragma unroll
    for (int u = 0; u < 3; ++u)
#pragma unroll
      for (int v = 0; v < 6; ++v) {
        const int tcol = 96 * wc + 16 * v + cpos;
        const int ii = c0 + tcol;
        const bool colok = (tcol <= TSTRIDE - 1) && (ii <= BROWS - 2);
#pragma unroll
        for (int r = 0; r < 4; ++r) {
          const int trow = 48 * wr + 16 * u + 4 * quad + r;
          const int jj = r0 + trow;
          float dl2, de2;
          if (r < 3) {
            dl2 = accl[u][v][r + 1];
            de2 = acce[u][v][r + 1];
          } else {
            const float dlq = __shfl(accl[u][v][0], (lane + 16) & 63, 64);
            const float deq = __shfl(acce[u][v][0], (lane + 16) & 63, 64);
            const int un = (u < 2) ? u + 1 : u;
            const float dlu = __shfl(accl[un][v][0], cpos, 64);
            const float deu = __shfl(acce[un][v][0], cpos, 64);
            if (quad < 3)    { dl2 = dlq; de2 = deq; }
            else if (u < 2)  { dl2 = dlu; de2 = deu; }
            else             { dl2 = hand_t[wr][tcol][0];   // wr==3 filtered
                               de2 = hand_t[wr][tcol][1]; }
          }
          if (colok && trow <= TSTRIDE - 1 && jj <= BROWS - 3) {
            const float dl1 = accl[u][v][r], de1 = acce[u][v][r];
            const float aa = dl1 - dl2, bb = de1 - de2;
            const float coeff = (float)((aa > 0.f) - (aa < 0.f)) -
                                (float)((bb > 0.f) - (bb < 0.f));
            sum += coeff * (de2 - de1);
          }
        }
      }
  }

  // ---- reduce + atomic ----
#pragma unroll
  for (int o = 32; o; o >>= 1) sum += __shfl_down(sum, o, 64);
  if (lane == 0) sred[wid] = sum;
  __syncthreads();
  if (tid == 0) {
    const float scale = 1.0f / ((float)(BROWS - 1) * (float)(BROWS - 2));
    float t = 0.f;
#pragma unroll
    for (int w = 0; w < 8; ++w) t += sred[w];
    atomicAdd(out, t * scale);
  }
}

// ===========================================================================
extern "C" void kernel_launch(void* const* d_in, const int* in_sizes, int n_in,
                              void* d_out, int out_size, void* d_ws,
                              size_t ws_size, hipStream_t stream) {
  const float* low = (const float*)d_in[0];
  const float* emb = (const float*)d_in[1];
  float* out = (float*)d_out;

  // ws: Yq (2*4096*512 fp8 = 4 MB) then s_l, r_l, s_e, r_e (4096 f32 each)
  unsigned char* Yq = (unsigned char*)d_ws;
  float* s_l = (float*)(Yq + 2 * (size_t)BROWS * DIM);
  float* r_l = s_l + BROWS;
  float* s_e = r_l + BROWS;
  float* r_e = s_e + BROWS;

  prep4_kernel<<<2 * BROWS / 4, 256, 0, stream>>>(low, emb, Yq, s_l, r_l, s_e, r_e, out);
  fused_sym_kernel<<<NT * (NT + 1) / 2, 512, 0, stream>>>(Yq, s_l, r_l, s_e, r_e, out);
}

// Round 19
// 107.832 us; speedup vs baseline: 1.1306x; 1.1306x over previous
//
#include <hip/hip_runtime.h>
#include <hip/hip_bf16.h>
#include <hip/hip_fp8.h>
#include <math.h>

#define BROWS 4096
#define DIM   512
#define YEMB_B 2097152   // 4096*512 bytes, offset of emb rows in Yq (fp8)
#define TSTRIDE 191      // tile stride (tiles are 192 wide, overlap by 1)
#define NT 22            // tiles per dim; triangle blocks = 22*23/2 = 253

typedef float f32x4 __attribute__((ext_vector_type(4)));

// ---------------------------------------------------------------------------
// prep4: wave-per-row, no barriers. 8192 rows (low then emb), 4 rows/block.
// L2-normalize -> fp8 e4m3 row in Yq; s=sum(y^2), r=sum(y) from f32 y.
// (verified R12-R31: absmax 0.0)
// ---------------------------------------------------------------------------
__global__ __launch_bounds__(256) void prep4_kernel(
    const float* __restrict__ low, const float* __restrict__ emb,
    unsigned char* __restrict__ Yq,
    float* __restrict__ s_l, float* __restrict__ r_l,
    float* __restrict__ s_e, float* __restrict__ r_e,
    float* __restrict__ out) {
  const int tid = threadIdx.x;
  const int lane = tid & 63, wid = tid >> 6;
  const int rid = blockIdx.x * 4 + wid;          // 0..8191
  if (blockIdx.x == 0 && tid == 0) out[0] = 0.f;

  const bool is_low = (rid < BROWS);
  const int row = is_low ? rid : rid - BROWS;
  const float* x = (is_low ? low : emb) + (size_t)row * DIM;

  const float4 v0 = ((const float4*)x)[lane * 2];
  const float4 v1 = ((const float4*)x)[lane * 2 + 1];

  float ss = v0.x * v0.x + v0.y * v0.y + v0.z * v0.z + v0.w * v0.w +
             v1.x * v1.x + v1.y * v1.y + v1.z * v1.z + v1.w * v1.w;
#pragma unroll
  for (int o = 1; o < 64; o <<= 1) ss += __shfl_xor(ss, o, 64);
  const float inv = 1.0f / fmaxf(sqrtf(ss), 1e-12f);

  float y[8] = {v0.x * inv, v0.y * inv, v0.z * inv, v0.w * inv,
                v1.x * inv, v1.y * inv, v1.z * inv, v1.w * inv};

  union { unsigned char b[8]; unsigned long long u; } pk;
  float sv = 0.f, rv = 0.f;
#pragma unroll
  for (int i = 0; i < 8; ++i) {
    pk.b[i] = __hip_fp8_e4m3(y[i]).__x;   // OCP e4m3fn, HW RNE
    sv += y[i] * y[i];
    rv += y[i];
  }
  ((unsigned long long*)(Yq + (size_t)rid * 512))[lane] = pk.u;

#pragma unroll
  for (int o = 1; o < 64; o <<= 1) {
    sv += __shfl_xor(sv, o, 64);
    rv += __shfl_xor(rv, o, 64);
  }
  if (lane == 0) {
    (is_low ? s_l : s_e)[row] = sv;
    (is_low ? r_l : r_e)[row] = rv;
  }
}

// ---------------------------------------------------------------------------
// R34 = exact resubmit of R18 (twice-verified best: 108.46/108.88 us total,
// fused 44.84/45.2 us, absmax 0.0, no spill). Final banking (rounds 17-18
// banking attempts lost to GPU acquisition timeouts; last successful bench
// on record is R31's 121.9 regression -> must restore the best).
// Session ledger: 8 falsified theories. R31 (A-direct-to-reg) regressed to
// 57.6 us fused: 12 scattered 8B/lane VMEM ops/round vs 3 coalesced 16B/lane
// global_load_lds — confirms round time scales with VMEM issue efficiency,
// and R18's staging is already optimal on that axis. R27's XCD swizzle cut
// FETCH 27% with no time delta (not HBM/L3-bound). Schedule (R18=R15),
// occupancy (R19), epilogue (R21), pipeline depth (R22) all neutral/worse.
// Geometry: 192x192 tiles (stride 191), NT=22 -> 253 blocks, 512 thr,
// 8 waves 4x2, wave tile 48x96 per matrix, acc 144 regs under (512,2) cap.
// K-loop: BK=64, 8 rounds, double-buffered 2x48 KB, counted vmcnt(6/3),
// never 0 until last round. LDS ~104 KB -> 1 block/CU, zero tail.
// MFMA f32_16x16x32_fp8_fp8; C/D: col=lane&15, row=(lane>>4)*4+reg.
// Epilogue: direct + transposed (symmetry) pair terms, shfl + LDS hands.
// ---------------------------------------------------------------------------
__global__ __launch_bounds__(512, 2) void fused_sym_kernel(
    const unsigned char* __restrict__ Yq,
    const float* __restrict__ s_l, const float* __restrict__ r_l,
    const float* __restrict__ s_e, const float* __restrict__ r_e,
    float* __restrict__ out) {
  __shared__ __align__(16) unsigned char lds8[98304];  // 2 x 48 KB buffers
  __shared__ float hand_d[4][48][2];    // dl/de at tile col 96, per wr
  __shared__ float hand_t[4][192][2];   // dl/de at tile row 48*wr ([wr-1])
  __shared__ float sred[8];

  // decode upper-triangle block id
  int rem = blockIdx.x, br = 0;
  while (rem >= NT - br) { rem -= NT - br; ++br; }
  const int bc = br + rem;
  const bool diag = (br == bc);

  const int tid = threadIdx.x;
  const int lane = tid & 63;
  const int wid = tid >> 6;          // 0..7
  const int wr = wid >> 1;           // 0..3: rows 48*wr..48*wr+47
  const int wc = wid & 1;            // 0..1: cols 96*wc..96*wc+95
  const int quad = lane >> 4, cpos = lane & 15;
  const int r0 = br * TSTRIDE, c0 = bc * TSTRIDE;

  // staging: 3072 slots of 16B per round (4 segs x 96 rp x 8 chunks);
  // thread owns slot c = tid + 512*s, s=0..5.  A segs = s<3, B segs = s>=3.
  int goff[6];   // BYTE offsets into Yq (add k0 = t*64 per round)
#pragma unroll
  for (int s = 0; s < 6; ++s) {
    const int c = tid + 512 * s;          // 0..3071
    const int seg = c / 768;
    const int within = c - seg * 768;
    const int rp = within >> 3;           // 0..95
    const int cc = within & 7;
    const int rloc = 2 * rp + (cc >> 2);
    const int gch = (cc & 3) ^ (rp & 3);  // swizzle
    int base;
    if (seg == 0)      base = min(r0 + rloc, BROWS - 1) * 512;
    else if (seg == 1) base = YEMB_B + min(r0 + rloc, BROWS - 1) * 512;
    else if (seg == 2) base = min(c0 + rloc, BROWS - 1) * 512;
    else               base = YEMB_B + min(c0 + rloc, BROWS - 1) * 512;
    goff[s] = base + (gch << 4);
  }

  auto STAGE = [&](int t, int b) {
    const int k0 = t * 64;
#pragma unroll
    for (int s = 0; s < 6; ++s) {
      if (s < 3 || !diag)   // s>=3 are B segments; skip when diag
        __builtin_amdgcn_global_load_lds(
            (const __attribute__((address_space(1))) void*)(Yq + goff[s] + k0),
            (__attribute__((address_space(3))) void*)(lds8 + b * 49152 +
                                                      (tid + 512 * s) * 16),
            16, 0, 0);
    }
  };

  // frag addressing (per 48 KB buffer): seg bytes Alow 0, Aemb 12288,
  // Blow 24576 (0 if diag), Bemb 36864 (12288 if diag); row-pair stride
  // 128 B; u/v stride 16 rows = 8 rp = 1024 B.
  const int RaH = (48 * wr + cpos) >> 1;     // row-pair idx (48wr even)
  const int s3a = RaH & 3;
  const int aoff = RaH * 128 + (cpos & 1) * 64 + (quad & 1) * 8;
  const int RbH = (96 * wc + cpos) >> 1;
  const int s3b = RbH & 3;
  const int boff = RbH * 128 + (cpos & 1) * 64 + (quad & 1) * 8;
  const int segAL = 0, segAE = 12288;
  const int segBL = diag ? 0 : 24576;
  const int segBE = diag ? 12288 : 36864;

  f32x4 accl[3][6], acce[3][6];
#pragma unroll
  for (int u = 0; u < 3; ++u)
#pragma unroll
    for (int v = 0; v < 6; ++v) {
      accl[u][v] = (f32x4)(0.f);
      acce[u][v] = (f32x4)(0.f);
    }

  STAGE(0, 0);   // prologue prefetch

  for (int t = 0; t < 8; ++t) {
    if (t < 7) STAGE(t + 1, (t + 1) & 1);   // buf free since barrier2 of t-1
    // counted wait: oldest 6 (3 diag) loads = round t's; keep t+1's in flight
    if (t == 7)      asm volatile("s_waitcnt vmcnt(0)" ::: "memory");
    else if (diag)   asm volatile("s_waitcnt vmcnt(3)" ::: "memory");
    else             asm volatile("s_waitcnt vmcnt(6)" ::: "memory");
    __builtin_amdgcn_s_barrier();
    __builtin_amdgcn_sched_barrier(0);

    const unsigned char* Lb = lds8 + (t & 1) * 49152;
#pragma unroll
    for (int kk = 0; kk < 2; ++kk) {
      const int q = 2 * kk + (quad >> 1);          // 16B chunk 0..3
      const int cha = aoff + ((q ^ s3a) << 4);
      const int chb = boff + ((q ^ s3b) << 4);
      {  // low matrix
        long a[3], b[6];
#pragma unroll
        for (int u = 0; u < 3; ++u) a[u] = *(const long*)(Lb + segAL + cha + u * 1024);
#pragma unroll
        for (int v = 0; v < 6; ++v) b[v] = *(const long*)(Lb + segBL + chb + v * 1024);
        __builtin_amdgcn_s_setprio(1);
#pragma unroll
        for (int u = 0; u < 3; ++u)
#pragma unroll
          for (int v = 0; v < 6; ++v)
            accl[u][v] = __builtin_amdgcn_mfma_f32_16x16x32_fp8_fp8(
                a[u], b[v], accl[u][v], 0, 0, 0);
        __builtin_amdgcn_s_setprio(0);
      }
      {  // emb matrix
        long a[3], b[6];
#pragma unroll
        for (int u = 0; u < 3; ++u) a[u] = *(const long*)(Lb + segAE + cha + u * 1024);
#pragma unroll
        for (int v = 0; v < 6; ++v) b[v] = *(const long*)(Lb + segBE + chb + v * 1024);
        __builtin_amdgcn_s_setprio(1);
#pragma unroll
        for (int u = 0; u < 3; ++u)
#pragma unroll
          for (int v = 0; v < 6; ++v)
            acce[u][v] = __builtin_amdgcn_mfma_f32_16x16x32_fp8_fp8(
                a[u], b[v], acce[u][v], 0, 0, 0);
        __builtin_amdgcn_s_setprio(0);
      }
    }
    __builtin_amdgcn_sched_barrier(0);
    __builtin_amdgcn_s_barrier();
    __builtin_amdgcn_sched_barrier(0);
  }

  // ---- transform both accs -> distances in place ----
  const float epst = (float)DIM * 1e-6f * 1e-6f;
#pragma unroll
  for (int v = 0; v < 6; ++v) {
    const int j = min(c0 + 96 * wc + 16 * v + cpos, BROWS - 1);
    const float sjl = s_l[j], rjl = r_l[j];
    const float sje = s_e[j], rje = r_e[j];
#pragma unroll
    for (int u = 0; u < 3; ++u)
#pragma unroll
      for (int r = 0; r < 4; ++r) {
        const int i = min(r0 + 48 * wr + 16 * u + 4 * quad + r, BROWS - 1);
        const float sql = s_l[i] + sjl - 2.f * accl[u][v][r] +
                          2e-6f * (r_l[i] - rjl) + epst;
        accl[u][v][r] = sqrtf(fmaxf(sql, 0.f));
        const float sqe = s_e[i] + sje - 2.f * acce[u][v][r] +
                          2e-6f * (r_e[i] - rje) + epst;
        acce[u][v][r] = sqrtf(fmaxf(sqe, 0.f));
      }
  }
  // now: dl in accl, de in acce

  // ---- publish cross-wave boundary values (dl and de) ----
  if (wc == 1 && cpos == 0) {   // tile col 96 for this wr's 48 rows
#pragma unroll
    for (int u = 0; u < 3; ++u)
#pragma unroll
      for (int r = 0; r < 4; ++r) {
        hand_d[wr][16 * u + 4 * quad + r][0] = accl[u][0][r];
        hand_d[wr][16 * u + 4 * quad + r][1] = acce[u][0][r];
      }
  }
  if (quad == 0 && wr >= 1) {   // tile row 48*wr (u=0,r=0) for 96 cols
#pragma unroll
    for (int v = 0; v < 6; ++v) {
      hand_t[wr - 1][96 * wc + 16 * v + cpos][0] = accl[0][v][0];
      hand_t[wr - 1][96 * wc + 16 * v + cpos][1] = acce[0][v][0];
    }
  }
  __syncthreads();

  float sum = 0.f;

  // ---- pass 1: direct terms (i in rows, pair cols j,j+1) ----
  const int srcin = (lane & 48) | ((cpos + 1) & 15);
#pragma unroll
  for (int u = 0; u < 3; ++u)
#pragma unroll
    for (int r = 0; r < 4; ++r) {
      const int trow = 48 * wr + 16 * u + 4 * quad + r;
      const int i = r0 + trow;
      const bool rowok = (trow <= TSTRIDE - 1) && (i <= BROWS - 2);
#pragma unroll
      for (int v = 0; v < 6; ++v) {
        const float dl1 = accl[u][v][r], de1 = acce[u][v][r];
        float dl2 = __shfl(dl1, srcin, 64);
        float de2 = __shfl(de1, srcin, 64);
        if (v < 5) {
          const float dlb = __shfl(accl[u][v + 1][r], lane & 48, 64);
          const float deb = __shfl(acce[u][v + 1][r], lane & 48, 64);
          if (cpos == 15) { dl2 = dlb; de2 = deb; }
        } else if (cpos == 15 && wc == 0) {
          dl2 = hand_d[wr][16 * u + 4 * quad + r][0];
          de2 = hand_d[wr][16 * u + 4 * quad + r][1];
        }
        const int tcol = 96 * wc + 16 * v + cpos;
        const int j = c0 + tcol;
        if (rowok && tcol <= TSTRIDE - 1 && j <= BROWS - 3) {
          const float aa = dl1 - dl2, bb = de1 - de2;
          const float coeff = (float)((aa > 0.f) - (aa < 0.f)) -
                              (float)((bb > 0.f) - (bb < 0.f));
          sum += coeff * (de2 - de1);
        }
      }
    }

  // ---- pass 2: transposed terms (i in cols, pair rows j,j+1), off-diag only ----
  if (!diag) {
#pragma unroll
    for (int u = 0; u < 3; ++u)
#pragma unroll
      for (int v = 0; v < 6; ++v) {
        const int tcol = 96 * wc + 16 * v + cpos;
        const int ii = c0 + tcol;
        const bool colok = (tcol <= TSTRIDE - 1) && (ii <= BROWS - 2);
#pragma unroll
        for (int r = 0; r < 4; ++r) {
          const int trow = 48 * wr + 16 * u + 4 * quad + r;
          const int jj = r0 + trow;
          float dl2, de2;
          if (r < 3) {
            dl2 = accl[u][v][r + 1];
            de2 = acce[u][v][r + 1];
          } else {
            const float dlq = __shfl(accl[u][v][0], (lane + 16) & 63, 64);
            const float deq = __shfl(acce[u][v][0], (lane + 16) & 63, 64);
            const int un = (u < 2) ? u + 1 : u;
            const float dlu = __shfl(accl[un][v][0], cpos, 64);
            const float deu = __shfl(acce[un][v][0], cpos, 64);
            if (quad < 3)    { dl2 = dlq; de2 = deq; }
            else if (u < 2)  { dl2 = dlu; de2 = deu; }
            else             { dl2 = hand_t[wr][tcol][0];   // wr==3 filtered
                               de2 = hand_t[wr][tcol][1]; }
          }
          if (colok && trow <= TSTRIDE - 1 && jj <= BROWS - 3) {
            const float dl1 = accl[u][v][r], de1 = acce[u][v][r];
            const float aa = dl1 - dl2, bb = de1 - de2;
            const float coeff = (float)((aa > 0.f) - (aa < 0.f)) -
                                (float)((bb > 0.f) - (bb < 0.f));
            sum += coeff * (de2 - de1);
          }
        }
      }
  }

  // ---- reduce + atomic ----
#pragma unroll
  for (int o = 32; o; o >>= 1) sum += __shfl_down(sum, o, 64);
  if (lane == 0) sred[wid] = sum;
  __syncthreads();
  if (tid == 0) {
    const float scale = 1.0f / ((float)(BROWS - 1) * (float)(BROWS - 2));
    float t = 0.f;
#pragma unroll
    for (int w = 0; w < 8; ++w) t += sred[w];
    atomicAdd(out, t * scale);
  }
}

// ===========================================================================
extern "C" void kernel_launch(void* const* d_in, const int* in_sizes, int n_in,
                              void* d_out, int out_size, void* d_ws,
                              size_t ws_size, hipStream_t stream) {
  const float* low = (const float*)d_in[0];
  const float* emb = (const float*)d_in[1];
  float* out = (float*)d_out;

  // ws: Yq (2*4096*512 fp8 = 4 MB) then s_l, r_l, s_e, r_e (4096 f32 each)
  unsigned char* Yq = (unsigned char*)d_ws;
  float* s_l = (float*)(Yq + 2 * (size_t)BROWS * DIM);
  float* r_l = s_l + BROWS;
  float* s_e = r_l + BROWS;
  float* r_e = s_e + BROWS;

  prep4_kernel<<<2 * BROWS / 4, 256, 0, stream>>>(low, emb, Yq, s_l, r_l, s_e, r_e, out);
  fused_sym_kernel<<<NT * (NT + 1) / 2, 512, 0, stream>>>(Yq, s_l, r_l, s_e, r_e, out);
}